// Round 5
// baseline (386.215 us; speedup 1.0000x reference)
//
#include <hip/hip_runtime.h>

#define NN 50000
#define EE 800000
#define EPT 256                 // edges per block-iteration (8 waves x 32)
#define NT8 (EE / EPT)          // 3125
#define NB ((NN + 1023) / 1024) // 49

typedef __attribute__((ext_vector_type(8))) short short8;
typedef __attribute__((ext_vector_type(16))) float f32x16;

static __device__ __forceinline__ unsigned short f2bf(float f) {
    unsigned u = __float_as_uint(f);
    u += 0x7fffu + ((u >> 16) & 1u);
    return (unsigned short)(u >> 16);
}
static __device__ __forceinline__ unsigned pack2(float a, float b) {
    return (unsigned)f2bf(a) | ((unsigned)f2bf(b) << 16);
}
static __device__ __forceinline__ float bf2f(unsigned short s) {
    return __uint_as_float((unsigned)s << 16);
}
static __device__ __forceinline__ f32x16 splat16(float v) {
    f32x16 r;
    #pragma unroll
    for (int i = 0; i < 16; ++i) r[i] = v;
    return r;
}

union U8 { short8 v; uint2 u[2]; };

// read an 8-bf16 MFMA fragment: elems [0..3] at k0, [4..7] at k0+8
static __device__ __forceinline__ short8 ldsfrag(const unsigned short* rowbase, int k0) {
    U8 t;
    t.u[0] = *(const uint2*)(rowbase + k0);
    t.u[1] = *(const uint2*)(rowbase + k0 + 8);
    return t.v;
}

// ---------------------------------------------------------------------------
// Kernel 1: Qh/Kh/Vh via MFMA. Block = 256 thr = 4 waves x 32 rows.
// ---------------------------------------------------------------------------
__global__ __launch_bounds__(256) void qkv_mfma_kernel(
    const float* __restrict__ x,
    const float* __restrict__ WQ, const float* __restrict__ WK, const float* __restrict__ WV,
    float* __restrict__ Qh, float* __restrict__ Kh, float* __restrict__ Vh)
{
    __shared__ unsigned short s_wq[64][66];
    __shared__ unsigned short s_wk[64][66];
    __shared__ unsigned short s_wv[64][66];

    int tid = threadIdx.x;
    #pragma unroll
    for (int t = 0; t < 16; ++t) {
        int idx = t * 256 + tid;
        int r = idx >> 6, c = idx & 63;
        s_wq[r][c] = f2bf(WQ[idx]);
        s_wk[r][c] = f2bf(WK[idx]);
        s_wv[r][c] = f2bf(WV[idx]);
    }
    __syncthreads();

    int wid = tid >> 6, lane = tid & 63;
    int m0 = blockIdx.x * 128 + wid * 32;
    int lo5 = lane & 31, hi = lane >> 5;

    int rowi = m0 + lo5;
    const float* arow = x + (size_t)(rowi < NN ? rowi : NN - 1) * 64;
    short8 af[4];
    #pragma unroll
    for (int ks = 0; ks < 4; ++ks) {
        int k0 = ks * 16 + hi * 4;
        float4 a0 = *(const float4*)(arow + k0);
        float4 a1 = *(const float4*)(arow + k0 + 8);
        U8 t;
        t.u[0] = make_uint2(pack2(a0.x, a0.y), pack2(a0.z, a0.w));
        t.u[1] = make_uint2(pack2(a1.x, a1.y), pack2(a1.z, a1.w));
        af[ks] = t.v;
    }

    #pragma unroll
    for (int nt = 0; nt < 2; ++nt) {
        int n = nt * 32 + lo5;
        f32x16 cQ = splat16(0.f), cK = splat16(0.f), cV = splat16(0.f);
        #pragma unroll
        for (int ks = 0; ks < 4; ++ks) {
            int k0 = ks * 16 + hi * 4;
            cQ = __builtin_amdgcn_mfma_f32_32x32x16_bf16(af[ks], ldsfrag(s_wq[n], k0), cQ, 0, 0, 0);
            cK = __builtin_amdgcn_mfma_f32_32x32x16_bf16(af[ks], ldsfrag(s_wk[n], k0), cK, 0, 0, 0);
            cV = __builtin_amdgcn_mfma_f32_32x32x16_bf16(af[ks], ldsfrag(s_wv[n], k0), cV, 0, 0, 0);
        }
        #pragma unroll
        for (int r = 0; r < 16; ++r) {
            int m = (r & 3) + 8 * (r >> 2) + 4 * hi;
            int gm = m0 + m;
            if (gm < NN) {
                Qh[(size_t)gm * 64 + n] = cQ[r];
                Kh[(size_t)gm * 64 + n] = cK[r];
                Vh[(size_t)gm * 64 + n] = cV[r];
            }
        }
    }
}

// ---------------------------------------------------------------------------
// CSR build: histogram -> hierarchical scan -> scatter (combined int2 + inv)
// ---------------------------------------------------------------------------
__global__ __launch_bounds__(256) void hist_kernel(const int* __restrict__ eidx,
                                                   int* __restrict__ cnt)
{
    int e = blockIdx.x * blockDim.x + threadIdx.x;
    atomicAdd(&cnt[eidx[e]], 1);
}

__global__ __launch_bounds__(1024) void scan1_kernel(const int* __restrict__ cnt,
                                                     int* __restrict__ rowstart,
                                                     int* __restrict__ bsum)
{
    __shared__ int buf[1024];
    int tid = threadIdx.x;
    int i = blockIdx.x * 1024 + tid;
    int v = (i < NN) ? cnt[i] : 0;
    buf[tid] = v;
    __syncthreads();
    for (int off = 1; off < 1024; off <<= 1) {
        int t = (tid >= off) ? buf[tid - off] : 0;
        __syncthreads();
        buf[tid] += t;
        __syncthreads();
    }
    if (i < NN) rowstart[i] = buf[tid] - v;
    if (tid == 1023) bsum[blockIdx.x] = buf[1023];
}

__global__ __launch_bounds__(64) void scan2_kernel(const int* __restrict__ bsum,
                                                   int* __restrict__ boff,
                                                   int* __restrict__ rowstart)
{
    int lane = threadIdx.x;
    int v = (lane < NB) ? bsum[lane] : 0;
    int s = v;
    #pragma unroll
    for (int off = 1; off < 64; off <<= 1) {
        int t = __shfl_up(s, off, 64);
        if (lane >= off) s += t;
    }
    if (lane < NB) boff[lane] = s - v;
    if (lane == 63) rowstart[NN] = s;
}

__global__ __launch_bounds__(1024) void scan3_kernel(int* __restrict__ rowstart,
                                                     const int* __restrict__ boff,
                                                     int* __restrict__ cursor)
{
    int i = blockIdx.x * 1024 + threadIdx.x;
    if (i < NN) {
        int r = rowstart[i] + boff[blockIdx.x];
        rowstart[i] = r;
        cursor[i] = r;
    }
}

__global__ __launch_bounds__(256) void scatter_kernel(const int* __restrict__ eidx,
                                                      int* __restrict__ cursor,
                                                      int2* __restrict__ edges_csr,
                                                      int* __restrict__ inv)
{
    int e = blockIdx.x * blockDim.x + threadIdx.x;
    int dst = eidx[e];
    int pos = atomicAdd(&cursor[dst], 1);
    edges_csr[pos] = make_int2(e, eidx[EE + e]);
    inv[e] = pos;
}

// ---------------------------------------------------------------------------
// Kernel 2: per-edge MFMA pass. 512 thr = 8 waves x 32 edges, grid-stride.
//   Q/K gathered DIRECTLY in C-fragment layout (f32, coalesced 128B per
//   half-wave) -> no qk LDS staging. conn round-trips LDS only for the
//   A-fragment re-form. No barriers in the main loop.
// ---------------------------------------------------------------------------
__global__ __launch_bounds__(512) void edge_mfma_kernel(
    const float* __restrict__ eattr, const int* __restrict__ eidx,
    const int* __restrict__ inv,
    const float* __restrict__ WEw, const float* __restrict__ WEb, const float* __restrict__ bEb,
    const float* __restrict__ WEo, const float* __restrict__ bEo, const float* __restrict__ Aw,
    const float* __restrict__ Qh, const float* __restrict__ Kh,
    float* __restrict__ Eo_out, float* __restrict__ exbuf)
{
    __shared__ unsigned short s_wew[64][66];
    __shared__ unsigned short s_web[64][66];
    __shared__ unsigned short s_weo[64][66];
    __shared__ unsigned short s_conn[8][32][66];

    int tid = threadIdx.x;
    #pragma unroll
    for (int t = 0; t < 8; ++t) {
        int idx = t * 512 + tid;
        int r = idx >> 6, c = idx & 63;
        s_wew[r][c] = f2bf(WEw[idx]);
        s_web[r][c] = f2bf(WEb[idx]);
        s_weo[r][c] = f2bf(WEo[idx]);
    }
    __syncthreads();

    int wid = tid >> 6, lane = tid & 63;
    int lo5 = lane & 31, hi = lane >> 5;

    // Aw values matching this lane's A-fragment elements:
    // elem (ks,i) -> k = ks*16 + hi*4 + (i&3) + ((i>>2)<<3); Aw[(k&7)*8 + (k>>3)]
    float awv[32];
    #pragma unroll
    for (int ks = 0; ks < 4; ++ks)
        #pragma unroll
        for (int i = 0; i < 8; ++i) {
            int k = ks * 16 + hi * 4 + (i & 3) + ((i >> 2) << 3);
            awv[ks * 8 + i] = Aw[(k & 7) * 8 + (k >> 3)];
        }
    float bEbn0 = bEb[lo5], bEbn1 = bEb[32 + lo5];
    float bEon0 = bEo[lo5], bEon1 = bEo[32 + lo5];

    for (int tile = blockIdx.x; tile < NT8; tile += gridDim.x) {
        int e0 = tile * EPT + wid * 32;
        int pos = inv[e0 + lo5];

        // eattr A-fragments
        short8 af[4];
        {
            const float* arow = eattr + (size_t)(e0 + lo5) * 64;
            #pragma unroll
            for (int ks = 0; ks < 4; ++ks) {
                int k0 = ks * 16 + hi * 4;
                float4 a0 = *(const float4*)(arow + k0);
                float4 a1 = *(const float4*)(arow + k0 + 8);
                U8 t;
                t.u[0] = make_uint2(pack2(a0.x, a0.y), pack2(a0.z, a0.w));
                t.u[1] = make_uint2(pack2(a1.x, a1.y), pack2(a1.z, a1.w));
                af[ks] = t.v;
            }
        }

        // per 32-col tile: direct C-layout qk gather + Ew/Eb GEMM + conn
        #pragma unroll
        for (int nt = 0; nt < 2; ++nt) {
            int n = nt * 32 + lo5;

            // qk[r] = Qh[dst(m)][n] + Kh[src(m)][n], m = (r&3)+8*(r>>2)+4*hi.
            // For fixed (r,hi): 32 lo5-lanes read consecutive floats -> 128B.
            float qk[16];
            #pragma unroll
            for (int rr = 0; rr < 4; ++rr) {
                int4 d4 = *(const int4*)(eidx + e0 + rr * 8 + hi * 4);
                int4 s4 = *(const int4*)(eidx + EE + e0 + rr * 8 + hi * 4);
                qk[rr * 4 + 0] = Qh[(size_t)d4.x * 64 + n] + Kh[(size_t)s4.x * 64 + n];
                qk[rr * 4 + 1] = Qh[(size_t)d4.y * 64 + n] + Kh[(size_t)s4.y * 64 + n];
                qk[rr * 4 + 2] = Qh[(size_t)d4.z * 64 + n] + Kh[(size_t)s4.z * 64 + n];
                qk[rr * 4 + 3] = Qh[(size_t)d4.w * 64 + n] + Kh[(size_t)s4.w * 64 + n];
            }

            f32x16 cEw = splat16(0.f), cEb = splat16(0.f);
            #pragma unroll
            for (int ks = 0; ks < 4; ++ks) {
                int k0 = ks * 16 + hi * 4;
                cEw = __builtin_amdgcn_mfma_f32_32x32x16_bf16(af[ks], ldsfrag(s_wew[n], k0), cEw, 0, 0, 0);
                cEb = __builtin_amdgcn_mfma_f32_32x32x16_bf16(af[ks], ldsfrag(s_web[n], k0), cEb, 0, 0, 0);
            }
            float bEbn = nt ? bEbn1 : bEbn0;
            #pragma unroll
            for (int r = 0; r < 16; ++r) {
                int m = (r & 3) + 8 * (r >> 2) + 4 * hi;
                float c1 = qk[r] * cEw[r];
                float c2 = copysignf(sqrtf(fabsf(c1)), c1);
                s_conn[wid][m][n] = f2bf(c2 + cEb[r] + bEbn);
            }
        }

        // conn A-fragments (same-wave ds_write->ds_read, program order)
        short8 ca[4];
        #pragma unroll
        for (int ks = 0; ks < 4; ++ks) {
            int k0 = ks * 16 + hi * 4;
            ca[ks] = ldsfrag(s_conn[wid][lo5], k0);
        }

        // score on VALU: elem (ks,i) -> h = 2ks + (i>>2); shfl_xor(32) joins halves
        {
            float sc[8];
            #pragma unroll
            for (int h2 = 0; h2 < 8; ++h2) sc[h2] = 0.f;
            #pragma unroll
            for (int ks = 0; ks < 4; ++ks)
                #pragma unroll
                for (int i = 0; i < 8; ++i) {
                    float cv = bf2f((unsigned short)ca[ks][i]);
                    sc[2 * ks + (i >> 2)] = fmaf(cv, awv[ks * 8 + i], sc[2 * ks + (i >> 2)]);
                }
            #pragma unroll
            for (int h2 = 0; h2 < 8; ++h2) {
                sc[h2] += __shfl_xor(sc[h2], 32, 64);
                sc[h2] = fminf(fmaxf(sc[h2], -5.0f), 5.0f);
                sc[h2] = __expf(sc[h2]);
            }
            if (hi == 0) {   // CSR-ordered ex writes
                *(float4*)(exbuf + (size_t)pos * 8 + 0) = make_float4(sc[0], sc[1], sc[2], sc[3]);
                *(float4*)(exbuf + (size_t)pos * 8 + 4) = make_float4(sc[4], sc[5], sc[6], sc[7]);
            }
        }

        // Eo GEMM (+bias) -> output (e-ordered, coalesced)
        #pragma unroll
        for (int nt = 0; nt < 2; ++nt) {
            int n = nt * 32 + lo5;
            f32x16 cO = splat16(nt ? bEon1 : bEon0);
            #pragma unroll
            for (int ks = 0; ks < 4; ++ks) {
                int k0 = ks * 16 + hi * 4;
                cO = __builtin_amdgcn_mfma_f32_32x32x16_bf16(ca[ks], ldsfrag(s_weo[n], k0), cO, 0, 0, 0);
            }
            #pragma unroll
            for (int r = 0; r < 16; ++r) {
                int m = (r & 3) + 8 * (r >> 2) + 4 * hi;
                Eo_out[(size_t)(e0 + m) * 64 + n] = cO[r];
            }
        }
    }
}

// ---------------------------------------------------------------------------
// Kernel 3: node aggregation (CSR). One wave per node; lane = (h,d).
// ---------------------------------------------------------------------------
__global__ __launch_bounds__(256) void node_kernel(
    const int* __restrict__ rowstart, const int2* __restrict__ edges_csr,
    const float* __restrict__ exbuf, const float* __restrict__ Eo,
    const float* __restrict__ Vh, const float* __restrict__ BW,
    float* __restrict__ hout)
{
    int n = (blockIdx.x * blockDim.x + threadIdx.x) >> 6;
    int lane = threadIdx.x & 63;
    int h = lane >> 3, d = lane & 7;

    int beg = rowstart[n], end = rowstart[n + 1];
    float agg0 = 0.f, rv0 = 0.f, den0 = 0.f;
    float agg1 = 0.f, rv1 = 0.f, den1 = 0.f;
    int j = beg;
    for (; j + 1 < end; j += 2) {
        int2 ea = edges_csr[j];
        int2 eb = edges_csr[j + 1];
        float xa = exbuf[(size_t)j * 8 + h];
        float xb = exbuf[(size_t)(j + 1) * 8 + h];
        agg0 = fmaf(xa, Vh[(size_t)ea.y * 64 + lane], agg0);
        rv0  = fmaf(xa, Eo[(size_t)ea.x * 64 + lane], rv0);
        den0 += xa;
        agg1 = fmaf(xb, Vh[(size_t)eb.y * 64 + lane], agg1);
        rv1  = fmaf(xb, Eo[(size_t)eb.x * 64 + lane], rv1);
        den1 += xb;
    }
    if (j < end) {
        int2 ea = edges_csr[j];
        float xa = exbuf[(size_t)j * 8 + h];
        agg0 = fmaf(xa, Vh[(size_t)ea.y * 64 + lane], agg0);
        rv0  = fmaf(xa, Eo[(size_t)ea.x * 64 + lane], rv0);
        den0 += xa;
    }
    float agg = agg0 + agg1, rv = rv0 + rv1, den = den0 + den1;
    float inv = (den > 0.f) ? (1.0f / den) : 0.f;

    float acc = agg;
    #pragma unroll
    for (int dd = 0; dd < 8; ++dd) {
        float rvd = __shfl(rv, (h << 3) + dd, 64);
        acc = fmaf(rvd, BW[dd * 64 + (h << 3) + d], acc);
    }
    hout[(size_t)n * 64 + lane] = acc * inv;
}

// ---------------------------------------------------------------------------
extern "C" void kernel_launch(void* const* d_in, const int* in_sizes, int n_in,
                              void* d_out, int out_size, void* d_ws, size_t ws_size,
                              hipStream_t stream)
{
    const float* x    = (const float*)d_in[0];
    const float* ea   = (const float*)d_in[1];
    const int*   eidx = (const int*)  d_in[2];
    const float* WQ   = (const float*)d_in[3];
    const float* WK   = (const float*)d_in[4];
    const float* WV   = (const float*)d_in[5];
    const float* WEw  = (const float*)d_in[6];
    const float* WEb  = (const float*)d_in[7];
    const float* bEb  = (const float*)d_in[8];
    const float* WEo  = (const float*)d_in[9];
    const float* bEo  = (const float*)d_in[10];
    const float* Aw   = (const float*)d_in[11];
    const float* BW   = (const float*)d_in[12];

    float* hout   = (float*)d_out;
    float* Eo_out = hout + (size_t)NN * 64;

    float* Qh    = (float*)d_ws;
    float* Kh    = Qh + (size_t)NN * 64;
    float* Vh    = Kh + (size_t)NN * 64;
    float* exbuf = Vh + (size_t)NN * 64;
    int* cnt      = (int*)(exbuf + (size_t)EE * 8);  // doubles as cursor
    int* rowstart = cnt + NN;                        // NN+2 (pad to 8B align)
    int2* edges_csr = (int2*)(rowstart + NN + 2);
    int* invp     = (int*)(edges_csr + EE);
    int* bsum     = invp + EE;
    int* boff     = bsum + 64;

    hipMemsetAsync(cnt, 0, (size_t)NN * sizeof(int), stream);

    hist_kernel<<<EE / 256, 256, 0, stream>>>(eidx, cnt);
    scan1_kernel<<<NB, 1024, 0, stream>>>(cnt, rowstart, bsum);
    scan2_kernel<<<1, 64, 0, stream>>>(bsum, boff, rowstart);
    scan3_kernel<<<NB, 1024, 0, stream>>>(rowstart, boff, cnt);
    scatter_kernel<<<EE / 256, 256, 0, stream>>>(eidx, cnt, edges_csr, invp);

    qkv_mfma_kernel<<<(NN + 127) / 128, 256, 0, stream>>>(x, WQ, WK, WV, Qh, Kh, Vh);

    edge_mfma_kernel<<<512, 512, 0, stream>>>(ea, eidx, invp, WEw, WEb, bEb, WEo, bEo, Aw,
                                              Qh, Kh, Eo_out, exbuf);

    node_kernel<<<(NN * 64) / 256, 256, 0, stream>>>(rowstart, edges_csr,
                                                     exbuf, Eo_out, Vh, BW, hout);
}